// Round 7
// baseline (233.422 us; speedup 1.0000x reference)
//
#include <hip/hip_runtime.h>
#include <stdint.h>

#define N_NODES 50000
#define E_EDGES 300000
#define C_CH    256
#define H_HEADS 8
#define NB2     64       // blocks in counting sort
#define CHUNK2  4688     // edges per sort block (64*4688 >= 300000)
#define NBIN    4096     // 256 dst x 16 src-ranges
#define SRCDIV  3125     // 50000/16 -> src-range = s/3125
#define NWG_GEMM 2346    // 391 m-tiles * 6 (mat,nh)

typedef unsigned short u16;
typedef unsigned int   u32;

typedef __attribute__((ext_vector_type(8))) short  v8s;   // 8 bf16 (MFMA A/B frag)
typedef __attribute__((ext_vector_type(4))) float  v4f;   // MFMA C/D frag

__device__ __forceinline__ float bf2f(u16 v) {
    union { u32 u; float f; } x; x.u = ((u32)v) << 16; return x.f;
}
__device__ __forceinline__ u16 f2bf(float f) {
    union { float f; u32 u; } x; x.f = f;
    u32 r = (x.u + 0x7FFFu + ((x.u >> 16) & 1u)) >> 16;
    return (u16)r;
}
__device__ __forceinline__ void unp2(u32 v, float& lo, float& hi) {
    union { u32 u; float f; } x;
    x.u = v << 16; lo = x.f;
    x.u = v & 0xFFFF0000u; hi = x.f;
}
// async global->LDS, 16 B/lane; LDS dest = wave-uniform base + lane*16
__device__ __forceinline__ void gl_lds16(const u16* g, u16* l) {
    __builtin_amdgcn_global_load_lds(
        (const __attribute__((address_space(1))) void*)g,
        (__attribute__((address_space(3))) void*)l, 16, 0, 0);
}
// 8 fp32 -> v8s bf16 via RNE hardware cvt (bit-identical to f2bf; verified
// passing in rounds 5 and 6)
__device__ __forceinline__ v8s cvt8(float4 a, float4 b) {
    union { u32 w[4]; v8s v; } r;
    asm("v_cvt_pk_bf16_f32 %0, %1, %2" : "=v"(r.w[0]) : "v"(a.x), "v"(a.y));
    asm("v_cvt_pk_bf16_f32 %0, %1, %2" : "=v"(r.w[1]) : "v"(a.z), "v"(a.w));
    asm("v_cvt_pk_bf16_f32 %0, %1, %2" : "=v"(r.w[2]) : "v"(b.x), "v"(b.y));
    asm("v_cvt_pk_bf16_f32 %0, %1, %2" : "=v"(r.w[3]) : "v"(b.z), "v"(b.w));
    return r.v;
}

// ---------------------------------------------------------------------------
// prep_k: blocks 0..191 convert Wk,Wv,Wq -> bf16 Wb; blocks 192..255 run the
// (dst, src-range) histogram + anchor bitmask.
// ---------------------------------------------------------------------------
__global__ __launch_bounds__(256) void prep_k(
    const float* __restrict__ Wk, const float* __restrict__ Wv,
    const float* __restrict__ Wq, u16* __restrict__ Wb,
    const int* __restrict__ src, const int* __restrict__ dst,
    u32* __restrict__ blockhist, u32* __restrict__ bintot,
    u32* __restrict__ inmask)
{
    __shared__ u32 hist[NBIN];
    int t = threadIdx.x, b = blockIdx.x;
    if (b < 192) {
        int m = (b < 64) ? 0 : (b < 128) ? 1 : 2;
        const float* sp = (m == 0) ? Wk : (m == 1) ? Wv : Wq;
        u16* dp = Wb + m * 65536;
        int i = (b & 63) * 1024 + t * 4;
        float4 v = *(const float4*)(sp + i);
        ushort4 o;
        o.x = f2bf(v.x); o.y = f2bf(v.y); o.z = f2bf(v.z); o.w = f2bf(v.w);
        *(ushort4*)(dp + i) = o;
        return;
    }
    int hb = b - 192;                        // 0..63
#pragma unroll
    for (int j = 0; j < 16; j++) hist[t + j * 256] = 0;
    __syncthreads();
    int start = hb * CHUNK2;
    int end = start + CHUNK2; if (end > E_EDGES) end = E_EDGES;
    for (int e = start + t; e < end; e += 256) {
        int d = dst[e], s = src[e];
        atomicAdd(&hist[d * 16 + s / SRCDIV], 1u);     // LDS atomic
        if (s < 256) atomicOr(&inmask[d * 8 + (s >> 5)], 1u << (s & 31));
    }
    __syncthreads();
#pragma unroll
    for (int j = 0; j < 16; j++) {
        int bin = t + j * 256;
        u32 h = hist[bin];
        blockhist[hb * NBIN + bin] = h;
        if (h) atomicAdd(&bintot[bin], h);
    }
}

// ---------------------------------------------------------------------------
// Megakernel: blocks 0..2345 = bf16 GEMM OUT[*,256] = bf16(x) @ W^T + bias.
// Round-7: EXACT round-4 structure (BK=32 dbuf, gl_lds B, reg-staged
// fp32->bf16 A, launch_bounds(256,4) -> 64 VGPR + 64 AGPR = 128 = 4 w/SIMD;
// round-6's (,3) gave 72+64=136 -> 3 w/SIMD and regressed 43->58us).
// Only additions vs round-4:
//  (1) K-loop 16B-slot XOR swizzle on A and B ([128][32] bf16 = 4 slots/row;
//      frag read was 8-way bank conflict).  A is reg-staged -> swizzle the
//      ds_write addr; B is gl_lds -> pre-swizzle the SOURCE col (rule #21);
//      reads apply the same XOR (slot ^ (row&3)).
//  (2) epilogue C-staging swizzle (verified -0.8M conflicts in round-6).
//  (3) cvt8 (4x v_cvt_pk_bf16_f32) instead of pack8 (~32 VALU ops).
// Block 2346 = scan of bintot -> bin_off.  Block 2347 = SPD reachability.
// ---------------------------------------------------------------------------
__global__ __launch_bounds__(256, 4) void gemm3(
    const float* __restrict__ x, const u16* __restrict__ Wb,
    const float* __restrict__ bk, const float* __restrict__ bv,
    const float* __restrict__ bq,
    u16* __restrict__ Kb, u16* __restrict__ Vb, u16* __restrict__ Qb,
    const u32* __restrict__ bintot, u32* __restrict__ bin_off,
    const u32* __restrict__ inmask, unsigned char* __restrict__ T)
{
    __shared__ u16 smem[4][128 * 32];   // A dbuf = smem[0,1], B dbuf = smem[2,3]
    const int t = threadIdx.x;

    if (blockIdx.x >= NWG_GEMM) {
        u32* b32 = (u32*)&smem[0][0];
        if (blockIdx.x == NWG_GEMM) {
            // ---- scan: exclusive scan bintot[4096] -> bin_off[4097] ----
            u32* tsum = b32;
            u32 loc[16]; u32 a = 0;
#pragma unroll
            for (int j = 0; j < 16; j++) { loc[j] = bintot[t * 16 + j]; a += loc[j]; }
            tsum[t] = a;
            __syncthreads();
            for (int off = 1; off < 256; off <<= 1) {
                u32 add = (t >= off) ? tsum[t - off] : 0u;
                __syncthreads();
                tsum[t] += add;
                __syncthreads();
            }
            u32 base = tsum[t] - a;
#pragma unroll
            for (int j = 0; j < 16; j++) { bin_off[t * 16 + j] = base; base += loc[j]; }
            if (t == 255) bin_off[NBIN] = base;
        } else {
            // ---- SPD: 3-level reachability on the 256-anchor subgraph ----
            u32 (*F1)[8] = (u32(*)[8])(b32);
            u32 (*F2)[8] = (u32(*)[8])(b32 + 2048);
            u32 (*F3)[8] = (u32(*)[8])(b32 + 4096);
            int i = t;
#pragma unroll
            for (int w = 0; w < 8; w++) { F1[i][w] = inmask[i * 8 + w]; F2[i][w] = 0; F3[i][w] = 0; }
            __syncthreads();
            for (int w = 0; w < 8; w++) {
                u32 m = F1[i][w];
                while (m) {
                    int b = __ffs(m) - 1; m &= m - 1;
                    int s = w * 32 + b;
#pragma unroll
                    for (int j = 0; j < 8; j++) F2[i][j] |= F1[s][j];
                }
            }
            __syncthreads();
            for (int w = 0; w < 8; w++) {
                u32 m = F1[i][w];
                while (m) {
                    int b = __ffs(m) - 1; m &= m - 1;
                    int s = w * 32 + b;
#pragma unroll
                    for (int j = 0; j < 8; j++) F3[i][j] |= F2[s][j];
                }
            }
            __syncthreads();
            for (int w = 0; w < 8; w++) {
                u32 f1 = F1[i][w], f2 = F2[i][w], f3 = F3[i][w];
#pragma unroll
                for (int g = 0; g < 8; g++) {
                    u32 word = 0;
#pragma unroll
                    for (int b = 0; b < 4; b++) {
                        int bit = g * 4 + b;
                        u32 k = ((f1 >> bit) & 1u) ? 1u : ((f2 >> bit) & 1u) ? 2u
                               : ((f3 >> bit) & 1u) ? 3u : 4u;
                        word |= k << (8 * b);
                    }
                    *(u32*)(T + i * 256 + w * 32 + g * 4) = word;
                }
            }
        }
        return;
    }

    // ---- GEMM ----
    // bijective XCD-chunked swizzle, m-tile-major: all 6 (mat,nh) blocks of
    // an m-tile share one XCD L2 -> fp32 A-panel fetched ~once from HBM.
    const int nwg = NWG_GEMM, q = nwg >> 3, r = nwg & 7;   // q=293, r=2
    int xcd = blockIdx.x & 7, pos = blockIdx.x >> 3;
    int wgid = (xcd < r ? xcd * (q + 1) : r * (q + 1) + (xcd - r) * q) + pos;
    const int mt = wgid / 6, j6 = wgid % 6;
    const int mat = j6 >> 1, nh = j6 & 1;
    const int m0 = mt * 128;
    if (mat == 2 && m0 >= 256) return;           // Q: only first 2 m-tiles
    const int M = (mat == 2) ? 256 : N_NODES;
    const u16* W = Wb + mat * 65536;
    const float* bias = (mat == 0) ? bk : (mat == 1) ? bv : bq;
    u16* OUT = (mat == 0) ? Kb : (mat == 1) ? Vb : Qb;
    const int n0 = nh * 128;

    const int lane = t & 63, w = t >> 6;
    const int quad = lane >> 4, l15 = lane & 15;
    const int mq = w & 1, nq = w >> 1;

    v4f acc[16];
#pragma unroll
    for (int i = 0; i < 16; i++) acc[i] = (v4f)(0.0f);

    // A staging (fp32 -> bf16 via regs): wave w covers rows w*32..+31.
    // lane -> rows {lrow, lrow+16}, fp32 cols (lane&3)*8..+7 per k-tile.
    // Rows clamped to 49999 (x has no pad rows); stores guarded by m<M.
    const int lrow = lane >> 2;               // 0..15
    const int lq   = lane & 3;
    const int cg   = lq * 8;                  // fp32 col-group (data w/ lane)
    int rA0 = m0 + w * 32 + lrow; if (rA0 > 49999) rA0 = 49999;
    int rA1 = rA0 + 16;           if (rA1 > 49999) rA1 = 49999;
    const float* gA0 = x + (size_t)rA0 * 256 + cg;
    const float* gA1 = x + (size_t)rA1 * 256 + cg;
    // B staging: global_load_lds; SOURCE 16B col-slot pre-swizzled by row&3
    // (dest is linear) so LDS[row][slot] = global[row][slot ^ (row&3)].
    const u16* gB = W + (size_t)(n0 + w * 32 + lrow) * 256
                      + (size_t)((lq ^ (lrow & 3)) * 8);

    // A ds_write addr: swizzled slot (lq ^ row&3); row+16 has same row&3.
    u16* ldsA = &smem[0][(w * 32 + lrow) * 32 + (lq ^ (lrow & 3)) * 8];

    float4 a00, a01, a10, a11;
#define LOADA(kt) do {                                   \
    a00 = *(const float4*)(gA0 + (kt) * 32);             \
    a01 = *(const float4*)(gA0 + (kt) * 32 + 4);         \
    a10 = *(const float4*)(gA1 + (kt) * 32);             \
    a11 = *(const float4*)(gA1 + (kt) * 32 + 4);         \
} while (0)
#define WRITEA(bi) do {                                  \
    *(v8s*)(ldsA + (bi) * 4096)           = cvt8(a00, a01); \
    *(v8s*)(ldsA + (bi) * 4096 + 16 * 32) = cvt8(a10, a11); \
} while (0)
#define STAGEB(bi, koff) do {                                             \
    gl_lds16(gB + (koff),            &smem[2 + (bi)][(w * 32) * 32]);     \
    gl_lds16(gB + 16 * 256 + (koff), &smem[2 + (bi)][(w * 32 + 16) * 32]);\
} while (0)

    LOADA(0);
    STAGEB(0, 0);
    WRITEA(0);
    __syncthreads();                          // drain prologue (vm + lgkm)
    for (int kt = 0; kt < 8; kt++) {
        const int cur = kt & 1;
        if (kt < 7) { LOADA(kt + 1); STAGEB(cur ^ 1, (kt + 1) * 32); }
        v8s a[4], b[4];
#pragma unroll
        for (int f = 0; f < 4; f++) {
            int ra = mq * 64 + f * 16 + l15;         // ra&3 == l15&3
            a[f] = *(const v8s*)(&smem[cur][ra * 32 + (quad ^ (l15 & 3)) * 8]);
        }
#pragma unroll
        for (int f = 0; f < 4; f++) {
            int rb = nq * 64 + f * 16 + l15;
            b[f] = *(const v8s*)(&smem[2 + cur][rb * 32 + (quad ^ (l15 & 3)) * 8]);
        }
#pragma unroll
        for (int fm = 0; fm < 4; fm++)
#pragma unroll
            for (int fn = 0; fn < 4; fn++)
                acc[fm * 4 + fn] = __builtin_amdgcn_mfma_f32_16x16x32_bf16(
                    a[fm], b[fn], acc[fm * 4 + fn], 0, 0, 0);
        if (kt < 7) WRITEA(cur ^ 1);          // fp32 loads landed under MFMA
        __syncthreads();                      // drains vm (B) + lgkm (A writes)
    }
#undef LOADA
#undef WRITEA
#undef STAGEB

    // Epilogue: stage C+bias into LDS with 16B-slot XOR swizzle
    // (slot' = (g&8) | ((g^row)&7), same on write+read — verified r6),
    // then coalesced uint4 stores (full 64 B lines -> no write amp).
    u16* S = &smem[0][0];
#pragma unroll
    for (int fn = 0; fn < 4; fn++) {
        int n = nq * 64 + fn * 16 + l15;
        float bi = bias[n0 + n];
        int g = n >> 3;
#pragma unroll
        for (int fm = 0; fm < 4; fm++) {
#pragma unroll
            for (int r2 = 0; r2 < 4; r2++) {
                int row = mq * 64 + fm * 16 + quad * 4 + r2;
                int gp = (g & 8) | ((g ^ row) & 7);
                S[row * 128 + gp * 8 + (n & 7)] = f2bf(acc[fm * 4 + fn][r2] + bi);
            }
        }
    }
    __syncthreads();
#pragma unroll
    for (int i = 0; i < 8; i++) {
        int c = i * 256 + t;
        int row = c >> 4;
        int g = c & 15;
        int gp = (g & 8) | ((g ^ row) & 7);
        int m = m0 + row;
        if (m < M)
            *(uint4*)(OUT + (size_t)m * 256 + n0 + g * 8) =
                *(const uint4*)(S + row * 128 + gp * 8);
    }
}

// ---------------------------------------------------------------------------
// Sort pass 3 (16 blocks): per-(sortblock,bin) base = bin_off + block prefix.
// All 64 histogram values prefetched into regs (one latency), prefix in regs.
// ---------------------------------------------------------------------------
__global__ __launch_bounds__(256) void base_k(
    const u32* __restrict__ blockhist, const u32* __restrict__ bin_off,
    u32* __restrict__ blockbase)
{
    int bin = blockIdx.x * 256 + threadIdx.x;
    u32 h[NB2];
#pragma unroll
    for (int b = 0; b < NB2; b++) h[b] = blockhist[b * NBIN + bin];
    u32 run = bin_off[bin];
#pragma unroll
    for (int b = 0; b < NB2; b++) {
        blockbase[b * NBIN + bin] = run;
        run += h[b];
    }
}

// ---------------------------------------------------------------------------
// Sort pass 4: scatter SRC VALUES into (dst, src-range) buckets (LDS cursors).
// ---------------------------------------------------------------------------
__global__ __launch_bounds__(256) void scatter2_k(
    const int* __restrict__ src, const int* __restrict__ dst,
    const u32* __restrict__ blockbase, u32* __restrict__ ssrc)
{
    __shared__ u32 cur[NBIN];
    int t = threadIdx.x, b = blockIdx.x;
#pragma unroll
    for (int j = 0; j < 16; j++)
        cur[t + j * 256] = blockbase[b * NBIN + t + j * 256];
    __syncthreads();
    int start = b * CHUNK2;
    int end = start + CHUNK2; if (end > E_EDGES) end = E_EDGES;
    for (int e = start + t; e < end; e += 256) {
        int s = src[e];
        int bin = dst[e] * 16 + s / SRCDIV;
        u32 pos = atomicAdd(&cur[bin], 1u);   // LDS atomic
        ssrc[pos] = (u32)s;
    }
}

// ---------------------------------------------------------------------------
// Fused scores+aggregate.  blockIdx = d*16 + src-range p -> each block's K/V
// gather stays inside a 3.2 MB src window; blockIdx%8 == p%8 pins a window
// pair per XCD L2.  2-deep pipeline: src 2 iters ahead, K/V rows 1 ahead.
// ---------------------------------------------------------------------------
__global__ __launch_bounds__(256) void agg_k(
    const u32* __restrict__ ssrc, const u32* __restrict__ bin_off,
    const u16* __restrict__ Qb, const u16* __restrict__ Kb,
    const u16* __restrict__ Vb, const unsigned char* __restrict__ T,
    const float* __restrict__ spd_w, float* __restrict__ out,
    float* __restrict__ denom)
{
    __shared__ float red[4 * 256];
    __shared__ float dred[4 * 8];
    int bid = blockIdx.x;
    int d = bid >> 4;
    int t = threadIdx.x, lane = t & 63, wave = t >> 6;
    int half = lane >> 5, sl = lane & 31;
    int h = sl >> 2;                        // head = (sl*8)>>5
    u32 start = bin_off[bid], end = bin_off[bid + 1];

    uint4 qv = *(const uint4*)(Qb + (size_t)d * 256 + sl * 8);
    float q0,q1,q2,q3,q4,q5,q6,q7;
    unp2(qv.x,q0,q1); unp2(qv.y,q2,q3); unp2(qv.z,q4,q5); unp2(qv.w,q6,q7);
    float sw4 = spd_w[4 * 8 + h];           // spd=4 bias (src>=256, ~98.5%)

    float a0=0.f,a1=0.f,a2=0.f,a3=0.f,a4=0.f,a5=0.f,a6=0.f,a7=0.f,dsum=0.f;

    u32 i = start + (u32)(wave * 2 + half);  // 8 slots, stride 8
    int s_c = 0, s_n = 0;
    uint4 kv_c = make_uint4(0,0,0,0), vv_c = kv_c;
    if (i < end) {
        s_c = (int)ssrc[i];
        kv_c = *(const uint4*)(Kb + (size_t)s_c * 256 + sl * 8);
        vv_c = *(const uint4*)(Vb + (size_t)s_c * 256 + sl * 8);
        if (i + 8 < end) s_n = (int)ssrc[i + 8];
    }
    while (i < end) {
        u32 inx = i + 8;
        uint4 kv_n = kv_c, vv_n = vv_c;
        if (inx < end) {                    // issue next row loads (addr ready)
            kv_n = *(const uint4*)(Kb + (size_t)s_n * 256 + sl * 8);
            vv_n = *(const uint4*)(Vb + (size_t)s_n * 256 + sl * 8);
        }
        int s_nn = (inx + 8 < end) ? (int)ssrc[inx + 8] : 0;
        float k0,k1,k2,k3,k4,k5,k6,k7, v0,v1,v2,v3,v4,v5,v6,v7;
        unp2(kv_c.x,k0,k1); unp2(kv_c.y,k2,k3); unp2(kv_c.z,k4,k5); unp2(kv_c.w,k6,k7);
        unp2(vv_c.x,v0,v1); unp2(vv_c.y,v2,v3); unp2(vv_c.z,v4,v5); unp2(vv_c.w,v6,v7);
        float p = q0*k0+q1*k1+q2*k2+q3*k3+q4*k4+q5*k5+q6*k6+q7*k7;
        p += __shfl_xor(p, 1);
        p += __shfl_xor(p, 2);              // head dot over 4 lanes x 8 ch
        float bias = (s_c < 256) ? spd_w[(int)T[s_c * 256 + d] * 8 + h] : sw4;
        float wgt = __expf(p * 0.17677669529663689f + bias);
        a0 += wgt*v0; a1 += wgt*v1; a2 += wgt*v2; a3 += wgt*v3;
        a4 += wgt*v4; a5 += wgt*v5; a6 += wgt*v6; a7 += wgt*v7;
        if ((sl & 3) == 0) dsum += wgt;
        i = inx; s_c = s_n; s_n = s_nn; kv_c = kv_n; vv_c = vv_n;
    }
    a0 += __shfl_xor(a0,32); a1 += __shfl_xor(a1,32);
    a2 += __shfl_xor(a2,32); a3 += __shfl_xor(a3,32);
    a4 += __shfl_xor(a4,32); a5 += __shfl_xor(a5,32);
    a6 += __shfl_xor(a6,32); a7 += __shfl_xor(a7,32);
    dsum += __shfl_xor(dsum,32);
    if (half == 0) {
        *(float4*)(&red[wave * 256 + sl * 8])     = make_float4(a0,a1,a2,a3);
        *(float4*)(&red[wave * 256 + sl * 8 + 4]) = make_float4(a4,a5,a6,a7);
        if ((sl & 3) == 0) dred[wave * 8 + h] = dsum;
    }
    __syncthreads();
    float sAll = red[t] + red[256 + t] + red[512 + t] + red[768 + t];
    atomicAdd(&out[(size_t)d * 256 + t], sAll);
    if (t < 8) {
        float ds = dred[t] + dred[8 + t] + dred[16 + t] + dred[24 + t];
        atomicAdd(&denom[d * 8 + t], ds);
    }
}

// ---------------------------------------------------------------------------
// LayerNorm: h = out/denom (anchors only) + x.  deg is constant per row ->
// cancels exactly under LN; skipped.  One wave per node, fp32 in/out.
// ---------------------------------------------------------------------------
__global__ __launch_bounds__(256) void ln_k(
    const float* __restrict__ x, const float* __restrict__ out,
    const float* __restrict__ denom, const float* __restrict__ gamma,
    const float* __restrict__ beta, float* __restrict__ y)
{
    int n = blockIdx.x * 4 + (threadIdx.x >> 6);
    if (n >= N_NODES) return;
    int lane = threadIdx.x & 63;
    int ch = lane * 4;
    float4 xv = *(const float4*)(x + (size_t)n * 256 + ch);
    float h0 = xv.x, h1 = xv.y, h2 = xv.z, h3 = xv.w;
    if (n < 256) {
        float den = denom[n * 8 + (lane >> 3)];
        float inv = (den > 0.f) ? 1.0f / den : 0.0f;
        const float* op = out + (size_t)n * 256 + ch;
        h0 += op[0] * inv; h1 += op[1] * inv;
        h2 += op[2] * inv; h3 += op[3] * inv;
    }
    float s = h0 + h1 + h2 + h3;
#pragma unroll
    for (int off = 1; off < 64; off <<= 1) s += __shfl_xor(s, off);
    float mu = s * (1.0f / 256.0f);
    float d0 = h0 - mu, d1 = h1 - mu, d2 = h2 - mu, d3 = h3 - mu;
    float q = d0 * d0 + d1 * d1 + d2 * d2 + d3 * d3;
#pragma unroll
    for (int off = 1; off < 64; off <<= 1) q += __shfl_xor(q, off);
    float rstd = rsqrtf(q * (1.0f / 256.0f) + 1e-5f);
    float4 gv = *(const float4*)(gamma + ch);
    float4 bv = *(const float4*)(beta + ch);
    float4 o;
    o.x = d0 * rstd * gv.x + bv.x;
    o.y = d1 * rstd * gv.y + bv.y;
    o.z = d2 * rstd * gv.z + bv.z;
    o.w = d3 * rstd * gv.w + bv.w;
    *(float4*)(y + (size_t)n * 256 + ch) = o;
}

// ---------------------------------------------------------------------------
extern "C" void kernel_launch(void* const* d_in, const int* in_sizes, int n_in,
                              void* d_out, int out_size, void* d_ws, size_t ws_size,
                              hipStream_t stream)
{
    const float* x     = (const float*)d_in[0];
    const int*   src   = (const int*)d_in[1];
    const int*   dst   = (const int*)d_in[2];
    const float* Wq    = (const float*)d_in[3];
    const float* bq    = (const float*)d_in[4];
    const float* Wk    = (const float*)d_in[5];
    const float* bk    = (const float*)d_in[6];
    const float* Wv    = (const float*)d_in[7];
    const float* bv    = (const float*)d_in[8];
    const float* spd_w = (const float*)d_in[9];
    const float* gamma = (const float*)d_in[10];
    const float* beta  = (const float*)d_in[11];
    float* y = (float*)d_out;

    char* ws = (char*)d_ws;
    // --- zeroed region [0, 294912) ---
    float* denom     = (float*)(ws + 0);          //   8192 B
    float* outf      = (float*)(ws + 8192);       // 262144 B
    u32*   inmask    = (u32*)(ws + 270336);       //   8192 B
    u32*   bintot    = (u32*)(ws + 278528);       //  16384 B (zero ends 294912)
    // --- rest (all written before read) ---
    u32*   bin_off   = (u32*)(ws + 294912);       //  16388 B (pad to 311552)
    unsigned char* T = (unsigned char*)(ws + 311552); // 65536 B -> 377088
    u32*   blockhist = (u32*)(ws + 377088);       // 64*4096*4 = 1 MB -> 1425664
    u32*   blockbase = (u32*)(ws + 1425664);      // 1 MB -> 2474240
    u32*   ssrc      = (u32*)(ws + 2474240);      // 1.2 MB (pad) -> 3676416
    u16*   Qb        = (u16*)(ws + 3676416);      // 128 KB -> 3807488
    u16*   Kb        = (u16*)(ws + 3807488);      // 25.6 MB -> 29407488
    u16*   Vb        = (u16*)(ws + 29407488);     // 25.6 MB -> 55007488
    u16*   Wb        = (u16*)(ws + 55007488);     // 384 KB (end ~55.4 MB)

    hipMemsetAsync(d_ws, 0, 294912, stream);

    dim3 blk(256);
    prep_k<<<dim3(256), blk, 0, stream>>>(Wk, Wv, Wq, Wb, src, dst,
                                          blockhist, bintot, inmask);
    gemm3<<<dim3(NWG_GEMM + 2), blk, 0, stream>>>(x, Wb, bk, bv, bq,
                                                  Kb, Vb, Qb, bintot, bin_off,
                                                  inmask, T);
    base_k<<<dim3(16), blk, 0, stream>>>(blockhist, bin_off, blockbase);
    scatter2_k<<<dim3(NB2), blk, 0, stream>>>(src, dst, blockbase, ssrc);
    agg_k<<<dim3(NBIN), blk, 0, stream>>>(ssrc, bin_off, Qb, Kb, Vb, T, spd_w, outf, denom);
    ln_k<<<dim3((N_NODES + 3) / 4), blk, 0, stream>>>(x, outf, denom, gamma, beta, y);
}

// Round 8
// 202.382 us; speedup vs baseline: 1.1534x; 1.1534x over previous
//
#include <hip/hip_runtime.h>
#include <stdint.h>

#define N_NODES 50000
#define E_EDGES 300000
#define C_CH    256
#define H_HEADS 8
#define NB2     64       // blocks in counting sort
#define CHUNK2  4688     // edges per sort block (64*4688 >= 300000)
#define NBIN    4096     // 256 dst x 16 src-ranges
#define SRCDIV  3125     // 50000/16 -> src-range = s/3125
#define NWG_GEMM 2346    // 391 m-tiles * 6 (mat,nh)
#define NWG_LN   12436   // (50000-256)/4 ln-tail blocks appended to megakernel

typedef unsigned short u16;
typedef unsigned int   u32;

typedef __attribute__((ext_vector_type(8))) short  v8s;   // 8 bf16 (MFMA A/B frag)
typedef __attribute__((ext_vector_type(4))) float  v4f;   // MFMA C/D frag

__device__ __forceinline__ float bf2f(u16 v) {
    union { u32 u; float f; } x; x.u = ((u32)v) << 16; return x.f;
}
__device__ __forceinline__ u16 f2bf(float f) {
    union { float f; u32 u; } x; x.f = f;
    u32 r = (x.u + 0x7FFFu + ((x.u >> 16) & 1u)) >> 16;
    return (u16)r;
}
__device__ __forceinline__ void unp2(u32 v, float& lo, float& hi) {
    union { u32 u; float f; } x;
    x.u = v << 16; lo = x.f;
    x.u = v & 0xFFFF0000u; hi = x.f;
}
// async global->LDS, 16 B/lane; LDS dest = wave-uniform base + lane*16
__device__ __forceinline__ void gl_lds16(const u16* g, u16* l) {
    __builtin_amdgcn_global_load_lds(
        (const __attribute__((address_space(1))) void*)g,
        (__attribute__((address_space(3))) void*)l, 16, 0, 0);
}
// pack 8 fp32 -> 8 bf16, single 16B LDS store (round-4 exact)
__device__ __forceinline__ void pack8(const float4 p, const float4 q, u16* dst) {
    u16 tmp[8];
    tmp[0]=f2bf(p.x); tmp[1]=f2bf(p.y); tmp[2]=f2bf(p.z); tmp[3]=f2bf(p.w);
    tmp[4]=f2bf(q.x); tmp[5]=f2bf(q.y); tmp[6]=f2bf(q.z); tmp[7]=f2bf(q.w);
    *(uint4*)dst = *(const uint4*)tmp;
}

// ---------------------------------------------------------------------------
// prep_k: blocks 0..191 convert Wk,Wv,Wq -> bf16 Wb; blocks 192..255 run the
// (dst, src-range) histogram + anchor bitmask.
// ---------------------------------------------------------------------------
__global__ __launch_bounds__(256) void prep_k(
    const float* __restrict__ Wk, const float* __restrict__ Wv,
    const float* __restrict__ Wq, u16* __restrict__ Wb,
    const int* __restrict__ src, const int* __restrict__ dst,
    u32* __restrict__ blockhist, u32* __restrict__ bintot,
    u32* __restrict__ inmask)
{
    __shared__ u32 hist[NBIN];
    int t = threadIdx.x, b = blockIdx.x;
    if (b < 192) {
        int m = (b < 64) ? 0 : (b < 128) ? 1 : 2;
        const float* sp = (m == 0) ? Wk : (m == 1) ? Wv : Wq;
        u16* dp = Wb + m * 65536;
        int i = (b & 63) * 1024 + t * 4;
        float4 v = *(const float4*)(sp + i);
        ushort4 o;
        o.x = f2bf(v.x); o.y = f2bf(v.y); o.z = f2bf(v.z); o.w = f2bf(v.w);
        *(ushort4*)(dp + i) = o;
        return;
    }
    int hb = b - 192;                        // 0..63
#pragma unroll
    for (int j = 0; j < 16; j++) hist[t + j * 256] = 0;
    __syncthreads();
    int start = hb * CHUNK2;
    int end = start + CHUNK2; if (end > E_EDGES) end = E_EDGES;
    for (int e = start + t; e < end; e += 256) {
        int d = dst[e], s = src[e];
        atomicAdd(&hist[d * 16 + s / SRCDIV], 1u);     // LDS atomic
        if (s < 256) atomicOr(&inmask[d * 8 + (s >> 5)], 1u << (s & 31));
    }
    __syncthreads();
#pragma unroll
    for (int j = 0; j < 16; j++) {
        int bin = t + j * 256;
        u32 h = hist[bin];
        blockhist[hb * NBIN + bin] = h;
        if (h) atomicAdd(&bintot[bin], h);
    }
}

// ---------------------------------------------------------------------------
// Megakernel.  Blocks 0..2345: bf16 GEMM OUT[*,256] = bf16(x) @ W^T + bias —
// EXACT round-4 code (43.4us measured; rounds 5/6/7 proved every deviation
// at the 64-VGPR cliff regresses: r5 all-reg 94us, r6 (,3) 58us, r7 swizzles
// 69us w/ doubled scratch traffic and conflict-count unchanged).
// Block 2346 = scan of bintot -> bin_off.  Block 2347 = SPD reachability.
// Blocks 2348..14783: LayerNorm for nodes 256..49999 (depends only on x) —
// BW-bound work backfilling the latency-bound GEMM's idle memory pipe
// (gemm runs at 26% HBM); saves the serial 17us ln pass.
// ---------------------------------------------------------------------------
__global__ __launch_bounds__(256, 4) void gemm3(
    const float* __restrict__ x, const u16* __restrict__ Wb,
    const float* __restrict__ bk, const float* __restrict__ bv,
    const float* __restrict__ bq,
    u16* __restrict__ Kb, u16* __restrict__ Vb, u16* __restrict__ Qb,
    const u32* __restrict__ bintot, u32* __restrict__ bin_off,
    const u32* __restrict__ inmask, unsigned char* __restrict__ T,
    const float* __restrict__ gamma, const float* __restrict__ beta,
    float* __restrict__ y)
{
    __shared__ u16 smem[4][128 * 32];   // A dbuf = smem[0,1], B dbuf = smem[2,3]
    const int t = threadIdx.x;

    if (blockIdx.x >= NWG_GEMM + 2) {
        // ---- LayerNorm tail: nodes 256..49999 (no agg contribution) ----
        int n = (blockIdx.x - (NWG_GEMM + 2)) * 4 + (t >> 6) + 256;
        int lane = t & 63;
        int ch = lane * 4;
        float4 xv = *(const float4*)(x + (size_t)n * 256 + ch);
        float h0 = xv.x, h1 = xv.y, h2 = xv.z, h3 = xv.w;
        float s = h0 + h1 + h2 + h3;
#pragma unroll
        for (int off = 1; off < 64; off <<= 1) s += __shfl_xor(s, off);
        float mu = s * (1.0f / 256.0f);
        float d0 = h0 - mu, d1 = h1 - mu, d2 = h2 - mu, d3 = h3 - mu;
        float qq = d0 * d0 + d1 * d1 + d2 * d2 + d3 * d3;
#pragma unroll
        for (int off = 1; off < 64; off <<= 1) qq += __shfl_xor(qq, off);
        float rstd = rsqrtf(qq * (1.0f / 256.0f) + 1e-5f);
        float4 gv = *(const float4*)(gamma + ch);
        float4 bv = *(const float4*)(beta + ch);
        float4 o;
        o.x = d0 * rstd * gv.x + bv.x;
        o.y = d1 * rstd * gv.y + bv.y;
        o.z = d2 * rstd * gv.z + bv.z;
        o.w = d3 * rstd * gv.w + bv.w;
        *(float4*)(y + (size_t)n * 256 + ch) = o;
        return;
    }

    if (blockIdx.x >= NWG_GEMM) {
        u32* b32 = (u32*)&smem[0][0];
        if (blockIdx.x == NWG_GEMM) {
            // ---- scan: exclusive scan bintot[4096] -> bin_off[4097] ----
            u32* tsum = b32;
            u32 loc[16]; u32 a = 0;
#pragma unroll
            for (int j = 0; j < 16; j++) { loc[j] = bintot[t * 16 + j]; a += loc[j]; }
            tsum[t] = a;
            __syncthreads();
            for (int off = 1; off < 256; off <<= 1) {
                u32 add = (t >= off) ? tsum[t - off] : 0u;
                __syncthreads();
                tsum[t] += add;
                __syncthreads();
            }
            u32 base = tsum[t] - a;
#pragma unroll
            for (int j = 0; j < 16; j++) { bin_off[t * 16 + j] = base; base += loc[j]; }
            if (t == 255) bin_off[NBIN] = base;
        } else {
            // ---- SPD: 3-level reachability on the 256-anchor subgraph ----
            u32 (*F1)[8] = (u32(*)[8])(b32);
            u32 (*F2)[8] = (u32(*)[8])(b32 + 2048);
            u32 (*F3)[8] = (u32(*)[8])(b32 + 4096);
            int i = t;
#pragma unroll
            for (int w = 0; w < 8; w++) { F1[i][w] = inmask[i * 8 + w]; F2[i][w] = 0; F3[i][w] = 0; }
            __syncthreads();
            for (int w = 0; w < 8; w++) {
                u32 m = F1[i][w];
                while (m) {
                    int b = __ffs(m) - 1; m &= m - 1;
                    int s = w * 32 + b;
#pragma unroll
                    for (int j = 0; j < 8; j++) F2[i][j] |= F1[s][j];
                }
            }
            __syncthreads();
            for (int w = 0; w < 8; w++) {
                u32 m = F1[i][w];
                while (m) {
                    int b = __ffs(m) - 1; m &= m - 1;
                    int s = w * 32 + b;
#pragma unroll
                    for (int j = 0; j < 8; j++) F3[i][j] |= F2[s][j];
                }
            }
            __syncthreads();
            for (int w = 0; w < 8; w++) {
                u32 f1 = F1[i][w], f2 = F2[i][w], f3 = F3[i][w];
#pragma unroll
                for (int g = 0; g < 8; g++) {
                    u32 word = 0;
#pragma unroll
                    for (int b = 0; b < 4; b++) {
                        int bit = g * 4 + b;
                        u32 k = ((f1 >> bit) & 1u) ? 1u : ((f2 >> bit) & 1u) ? 2u
                               : ((f3 >> bit) & 1u) ? 3u : 4u;
                        word |= k << (8 * b);
                    }
                    *(u32*)(T + i * 256 + w * 32 + g * 4) = word;
                }
            }
        }
        return;
    }

    // ---- GEMM (round-4 exact) ----
    const int nwg = NWG_GEMM, q = nwg >> 3, r = nwg & 7;   // q=293, r=2
    int xcd = blockIdx.x & 7, pos = blockIdx.x >> 3;
    int wgid = (xcd < r ? xcd * (q + 1) : r * (q + 1) + (xcd - r) * q) + pos;
    const int mt = wgid / 6, j6 = wgid % 6;
    const int mat = j6 >> 1, nh = j6 & 1;
    const int m0 = mt * 128;
    if (mat == 2 && m0 >= 256) return;           // Q: only first 2 m-tiles
    const int M = (mat == 2) ? 256 : N_NODES;
    const u16* W = Wb + mat * 65536;
    const float* bias = (mat == 0) ? bk : (mat == 1) ? bv : bq;
    u16* OUT = (mat == 0) ? Kb : (mat == 1) ? Vb : Qb;
    const int n0 = nh * 128;

    const int lane = t & 63, w = t >> 6;
    const int quad = lane >> 4, l15 = lane & 15;
    const int mq = w & 1, nq = w >> 1;

    v4f acc[16];
#pragma unroll
    for (int i = 0; i < 16; i++) acc[i] = (v4f)(0.0f);

    const int lrow = lane >> 2;               // 0..15
    const int cg   = (lane & 3) * 8;          // fp32 col-group offset
    int rA0 = m0 + w * 32 + lrow; if (rA0 > 49999) rA0 = 49999;
    int rA1 = rA0 + 16;           if (rA1 > 49999) rA1 = 49999;
    const float* gA0 = x + (size_t)rA0 * 256 + cg;
    const float* gA1 = x + (size_t)rA1 * 256 + cg;
    const u16* gB = W + (size_t)(n0 + w * 32 + lrow) * 256 + (lane & 3) * 8;

    u16* ldsA = &smem[0][(w * 32 + lrow) * 32 + (lane & 3) * 8];

    float4 a00, a01, a10, a11;
#define LOADA(kt) do {                                   \
    a00 = *(const float4*)(gA0 + (kt) * 32);             \
    a01 = *(const float4*)(gA0 + (kt) * 32 + 4);         \
    a10 = *(const float4*)(gA1 + (kt) * 32);             \
    a11 = *(const float4*)(gA1 + (kt) * 32 + 4);         \
} while (0)
#define WRITEA(bi) do {                                  \
    pack8(a00, a01, ldsA + (bi) * 4096);                 \
    pack8(a10, a11, ldsA + (bi) * 4096 + 16 * 32);       \
} while (0)
#define STAGEB(bi, koff) do {                                             \
    gl_lds16(gB + (koff),            &smem[2 + (bi)][(w * 32) * 32]);     \
    gl_lds16(gB + 16 * 256 + (koff), &smem[2 + (bi)][(w * 32 + 16) * 32]);\
} while (0)

    LOADA(0);
    STAGEB(0, 0);
    WRITEA(0);
    __syncthreads();                          // drain prologue (vm + lgkm)
    for (int kt = 0; kt < 8; kt++) {
        const int cur = kt & 1;
        if (kt < 7) { LOADA(kt + 1); STAGEB(cur ^ 1, (kt + 1) * 32); }
        v8s a[4], b[4];
#pragma unroll
        for (int f = 0; f < 4; f++)
            a[f] = *(const v8s*)(&smem[cur][(mq * 64 + f * 16 + l15) * 32 + quad * 8]);
#pragma unroll
        for (int f = 0; f < 4; f++)
            b[f] = *(const v8s*)(&smem[2 + cur][(nq * 64 + f * 16 + l15) * 32 + quad * 8]);
#pragma unroll
        for (int fm = 0; fm < 4; fm++)
#pragma unroll
            for (int fn = 0; fn < 4; fn++)
                acc[fm * 4 + fn] = __builtin_amdgcn_mfma_f32_16x16x32_bf16(
                    a[fm], b[fn], acc[fm * 4 + fn], 0, 0, 0);
        if (kt < 7) WRITEA(cur ^ 1);          // fp32 loads landed under MFMA
        __syncthreads();                      // drains vm (B) + lgkm (A writes)
    }
#undef LOADA
#undef WRITEA
#undef STAGEB

    // Epilogue: stage C+bias into LDS (32 KB = all 4 buffers), coalesced
    // uint4 stores (full 64 B lines -> no write amplification).
    u16* S = &smem[0][0];
#pragma unroll
    for (int fn = 0; fn < 4; fn++) {
        int n = nq * 64 + fn * 16 + l15;
        float bi = bias[n0 + n];
#pragma unroll
        for (int fm = 0; fm < 4; fm++) {
#pragma unroll
            for (int r2 = 0; r2 < 4; r2++) {
                int row = mq * 64 + fm * 16 + quad * 4 + r2;
                S[row * 128 + n] = f2bf(acc[fm * 4 + fn][r2] + bi);
            }
        }
    }
    __syncthreads();
#pragma unroll
    for (int i = 0; i < 8; i++) {
        int c = i * 256 + t;
        int row = c >> 4;
        int m = m0 + row;
        if (m < M)
            *(uint4*)(OUT + (size_t)m * 256 + n0 + (c & 15) * 8) =
                *(const uint4*)(S + c * 8);
    }
}

// ---------------------------------------------------------------------------
// Sort pass 3 (16 blocks): per-(sortblock,bin) base = bin_off + block prefix.
// All 64 histogram values prefetched into regs (one latency), prefix in regs.
// ---------------------------------------------------------------------------
__global__ __launch_bounds__(256) void base_k(
    const u32* __restrict__ blockhist, const u32* __restrict__ bin_off,
    u32* __restrict__ blockbase)
{
    int bin = blockIdx.x * 256 + threadIdx.x;
    u32 h[NB2];
#pragma unroll
    for (int b = 0; b < NB2; b++) h[b] = blockhist[b * NBIN + bin];
    u32 run = bin_off[bin];
#pragma unroll
    for (int b = 0; b < NB2; b++) {
        blockbase[b * NBIN + bin] = run;
        run += h[b];
    }
}

// ---------------------------------------------------------------------------
// Sort pass 4: scatter SRC VALUES into (dst, src-range) buckets (LDS cursors).
// ---------------------------------------------------------------------------
__global__ __launch_bounds__(256) void scatter2_k(
    const int* __restrict__ src, const int* __restrict__ dst,
    const u32* __restrict__ blockbase, u32* __restrict__ ssrc)
{
    __shared__ u32 cur[NBIN];
    int t = threadIdx.x, b = blockIdx.x;
#pragma unroll
    for (int j = 0; j < 16; j++)
        cur[t + j * 256] = blockbase[b * NBIN + t + j * 256];
    __syncthreads();
    int start = b * CHUNK2;
    int end = start + CHUNK2; if (end > E_EDGES) end = E_EDGES;
    for (int e = start + t; e < end; e += 256) {
        int s = src[e];
        int bin = dst[e] * 16 + s / SRCDIV;
        u32 pos = atomicAdd(&cur[bin], 1u);   // LDS atomic
        ssrc[pos] = (u32)s;
    }
}

// ---------------------------------------------------------------------------
// Fused scores+aggregate.  blockIdx = d*16 + src-range p -> each block's K/V
// gather stays inside a 3.2 MB src window; blockIdx%8 == p%8 pins a window
// pair per XCD L2.  2-deep pipeline: src 2 iters ahead, K/V rows 1 ahead.
// ---------------------------------------------------------------------------
__global__ __launch_bounds__(256) void agg_k(
    const u32* __restrict__ ssrc, const u32* __restrict__ bin_off,
    const u16* __restrict__ Qb, const u16* __restrict__ Kb,
    const u16* __restrict__ Vb, const unsigned char* __restrict__ T,
    const float* __restrict__ spd_w, float* __restrict__ out,
    float* __restrict__ denom)
{
    __shared__ float red[4 * 256];
    __shared__ float dred[4 * 8];
    int bid = blockIdx.x;
    int d = bid >> 4;
    int t = threadIdx.x, lane = t & 63, wave = t >> 6;
    int half = lane >> 5, sl = lane & 31;
    int h = sl >> 2;                        // head = (sl*8)>>5
    u32 start = bin_off[bid], end = bin_off[bid + 1];

    uint4 qv = *(const uint4*)(Qb + (size_t)d * 256 + sl * 8);
    float q0,q1,q2,q3,q4,q5,q6,q7;
    unp2(qv.x,q0,q1); unp2(qv.y,q2,q3); unp2(qv.z,q4,q5); unp2(qv.w,q6,q7);
    float sw4 = spd_w[4 * 8 + h];           // spd=4 bias (src>=256, ~98.5%)

    float a0=0.f,a1=0.f,a2=0.f,a3=0.f,a4=0.f,a5=0.f,a6=0.f,a7=0.f,dsum=0.f;

    u32 i = start + (u32)(wave * 2 + half);  // 8 slots, stride 8
    int s_c = 0, s_n = 0;
    uint4 kv_c = make_uint4(0,0,0,0), vv_c = kv_c;
    if (i < end) {
        s_c = (int)ssrc[i];
        kv_c = *(const uint4*)(Kb + (size_t)s_c * 256 + sl * 8);
        vv_c = *(const uint4*)(Vb + (size_t)s_c * 256 + sl * 8);
        if (i + 8 < end) s_n = (int)ssrc[i + 8];
    }
    while (i < end) {
        u32 inx = i + 8;
        uint4 kv_n = kv_c, vv_n = vv_c;
        if (inx < end) {                    // issue next row loads (addr ready)
            kv_n = *(const uint4*)(Kb + (size_t)s_n * 256 + sl * 8);
            vv_n = *(const uint4*)(Vb + (size_t)s_n * 256 + sl * 8);
        }
        int s_nn = (inx + 8 < end) ? (int)ssrc[inx + 8] : 0;
        float k0,k1,k2,k3,k4,k5,k6,k7, v0,v1,v2,v3,v4,v5,v6,v7;
        unp2(kv_c.x,k0,k1); unp2(kv_c.y,k2,k3); unp2(kv_c.z,k4,k5); unp2(kv_c.w,k6,k7);
        unp2(vv_c.x,v0,v1); unp2(vv_c.y,v2,v3); unp2(vv_c.z,v4,v5); unp2(vv_c.w,v6,v7);
        float p = q0*k0+q1*k1+q2*k2+q3*k3+q4*k4+q5*k5+q6*k6+q7*k7;
        p += __shfl_xor(p, 1);
        p += __shfl_xor(p, 2);              // head dot over 4 lanes x 8 ch
        float bias = (s_c < 256) ? spd_w[(int)T[s_c * 256 + d] * 8 + h] : sw4;
        float wgt = __expf(p * 0.17677669529663689f + bias);
        a0 += wgt*v0; a1 += wgt*v1; a2 += wgt*v2; a3 += wgt*v3;
        a4 += wgt*v4; a5 += wgt*v5; a6 += wgt*v6; a7 += wgt*v7;
        if ((sl & 3) == 0) dsum += wgt;
        i = inx; s_c = s_n; s_n = s_nn; kv_c = kv_n; vv_c = vv_n;
    }
    a0 += __shfl_xor(a0,32); a1 += __shfl_xor(a1,32);
    a2 += __shfl_xor(a2,32); a3 += __shfl_xor(a3,32);
    a4 += __shfl_xor(a4,32); a5 += __shfl_xor(a5,32);
    a6 += __shfl_xor(a6,32); a7 += __shfl_xor(a7,32);
    dsum += __shfl_xor(dsum,32);
    if (half == 0) {
        *(float4*)(&red[wave * 256 + sl * 8])     = make_float4(a0,a1,a2,a3);
        *(float4*)(&red[wave * 256 + sl * 8 + 4]) = make_float4(a4,a5,a6,a7);
        if ((sl & 3) == 0) dred[wave * 8 + h] = dsum;
    }
    __syncthreads();
    float sAll = red[t] + red[256 + t] + red[512 + t] + red[768 + t];
    atomicAdd(&out[(size_t)d * 256 + t], sAll);
    if (t < 8) {
        float ds = dred[t] + dred[8 + t] + dred[16 + t] + dred[24 + t];
        atomicAdd(&denom[d * 8 + t], ds);
    }
}

// ---------------------------------------------------------------------------
// LayerNorm anchors (n < 256 only): h = out/denom + x.  Tail nodes were
// normalized inside the megakernel.  64 blocks.
// ---------------------------------------------------------------------------
__global__ __launch_bounds__(256) void ln_k(
    const float* __restrict__ x, const float* __restrict__ out,
    const float* __restrict__ denom, const float* __restrict__ gamma,
    const float* __restrict__ beta, float* __restrict__ y)
{
    int n = blockIdx.x * 4 + (threadIdx.x >> 6);
    int lane = threadIdx.x & 63;
    int ch = lane * 4;
    float4 xv = *(const float4*)(x + (size_t)n * 256 + ch);
    float h0 = xv.x, h1 = xv.y, h2 = xv.z, h3 = xv.w;
    float den = denom[n * 8 + (lane >> 3)];
    float inv = (den > 0.f) ? 1.0f / den : 0.0f;
    const float* op = out + (size_t)n * 256 + ch;
    h0 += op[0] * inv; h1 += op[1] * inv;
    h2 += op[2] * inv; h3 += op[3] * inv;
    float s = h0 + h1 + h2 + h3;
#pragma unroll
    for (int off = 1; off < 64; off <<= 1) s += __shfl_xor(s, off);
    float mu = s * (1.0f / 256.0f);
    float d0 = h0 - mu, d1 = h1 - mu, d2 = h2 - mu, d3 = h3 - mu;
    float q = d0 * d0 + d1 * d1 + d2 * d2 + d3 * d3;
#pragma unroll
    for (int off = 1; off < 64; off <<= 1) q += __shfl_xor(q, off);
    float rstd = rsqrtf(q * (1.0f / 256.0f) + 1e-5f);
    float4 gv = *(const float4*)(gamma + ch);
    float4 bv = *(const float4*)(beta + ch);
    float4 o;
    o.x = d0 * rstd * gv.x + bv.x;
    o.y = d1 * rstd * gv.y + bv.y;
    o.z = d2 * rstd * gv.z + bv.z;
    o.w = d3 * rstd * gv.w + bv.w;
    *(float4*)(y + (size_t)n * 256 + ch) = o;
}

// ---------------------------------------------------------------------------
extern "C" void kernel_launch(void* const* d_in, const int* in_sizes, int n_in,
                              void* d_out, int out_size, void* d_ws, size_t ws_size,
                              hipStream_t stream)
{
    const float* x     = (const float*)d_in[0];
    const int*   src   = (const int*)d_in[1];
    const int*   dst   = (const int*)d_in[2];
    const float* Wq    = (const float*)d_in[3];
    const float* bq    = (const float*)d_in[4];
    const float* Wk    = (const float*)d_in[5];
    const float* bk    = (const float*)d_in[6];
    const float* Wv    = (const float*)d_in[7];
    const float* bv    = (const float*)d_in[8];
    const float* spd_w = (const float*)d_in[9];
    const float* gamma = (const float*)d_in[10];
    const float* beta  = (const float*)d_in[11];
    float* y = (float*)d_out;

    char* ws = (char*)d_ws;
    // --- zeroed region [0, 294912) ---
    float* denom     = (float*)(ws + 0);          //   8192 B
    float* outf      = (float*)(ws + 8192);       // 262144 B
    u32*   inmask    = (u32*)(ws + 270336);       //   8192 B
    u32*   bintot    = (u32*)(ws + 278528);       //  16384 B (zero ends 294912)
    // --- rest (all written before read) ---
    u32*   bin_off   = (u32*)(ws + 294912);       //  16388 B (pad to 311552)
    unsigned char* T = (unsigned char*)(ws + 311552); // 65536 B -> 377088
    u32*   blockhist = (u32*)(ws + 377088);       // 64*4096*4 = 1 MB -> 1425664
    u32*   blockbase = (u32*)(ws + 1425664);      // 1 MB -> 2474240
    u32*   ssrc      = (u32*)(ws + 2474240);      // 1.2 MB (pad) -> 3676416
    u16*   Qb        = (u16*)(ws + 3676416);      // 128 KB -> 3807488
    u16*   Kb        = (u16*)(ws + 3807488);      // 25.6 MB -> 29407488
    u16*   Vb        = (u16*)(ws + 29407488);     // 25.6 MB -> 55007488
    u16*   Wb        = (u16*)(ws + 55007488);     // 384 KB (end ~55.4 MB)

    hipMemsetAsync(d_ws, 0, 294912, stream);

    dim3 blk(256);
    prep_k<<<dim3(256), blk, 0, stream>>>(Wk, Wv, Wq, Wb, src, dst,
                                          blockhist, bintot, inmask);
    gemm3<<<dim3(NWG_GEMM + 2 + NWG_LN), blk, 0, stream>>>(
        x, Wb, bk, bv, bq, Kb, Vb, Qb, bintot, bin_off, inmask, T,
        gamma, beta, y);
    base_k<<<dim3(16), blk, 0, stream>>>(blockhist, bin_off, blockbase);
    scatter2_k<<<dim3(NB2), blk, 0, stream>>>(src, dst, blockbase, ssrc);
    agg_k<<<dim3(NBIN), blk, 0, stream>>>(ssrc, bin_off, Qb, Kb, Vb, T, spd_w, outf, denom);
    ln_k<<<dim3(64), blk, 0, stream>>>(x, outf, denom, gamma, beta, y);
}